// Round 15
// baseline (73.823 us; speedup 1.0000x reference)
//
#include <hip/hip_runtime.h>

#define NBATCH 32
#define NSEG 255
#define SIGLEN 4680       // 8 + 64 + 512 + 4096
#define INV6 (1.0f/6.0f)
#define INV24 (1.0f/24.0f)

typedef float v2f __attribute__((ext_vector_type(2)));

// Commutative ("moment") form of the depth-4 signature over segments
// j = 0..254 (d_j = x_{j+1} - x_j), all per batch:
//   S1[e]    = (xT - x0)[e]
//   S2[ab]   = sum_k w_k,   w_k = d_k[b]*(x_k - x0)[a] + 0.5*d_k[a]*d_k[b]
//   Q_j[ab]  = d_a d_b/6  + (x_j-x0)[a] d_b/2 + S2pre_j[ab]
//   P_j[ab]  = d_a d_b/24 + (x_j-x0)[a] d_b/6 + S2pre_j[ab]/2
//   S3[abc]  = sum_j Q_j[ab] * d_j[c]
//   S4[abce] = sum_j d_j[c] * ( Q_j[ab]*(xT - x_{j+1})[e] + P_j[ab]*d_j[e] )
// where S2pre_j = sum_{k<j} w_k.  Every S3/S4 term is an independent summand
// given the cheap scalar prefix S2pre -> j-chunks combine by pure ADDITION.
//
// Grid: 256 blocks = 32 batches x 8 chunks of 32 segments. 512 threads =
// 8 waves = 4 pairs; pair pr handles 8 segments, halves h split c-range.
// Cross-block combine: hardware f32 atomicAdd into zeroed d_out.
__global__ __launch_bounds__(512)
__attribute__((amdgpu_waves_per_eu(2, 2)))
void sig_kernel(const float* __restrict__ path, float* __restrict__ out) {
    const int blk = blockIdx.x;
    const int n = blk >> 3, cb = blk & 7;
    const int t = threadIdx.x;
    const int w = t >> 6, l = t & 63, a = l >> 3, b = l & 7;
    const int pr = w >> 1, h = w & 1;

    __shared__ float pbuf[2048];      // path row
    __shared__ float dbuf[2048];      // d_j (j=255 -> 0)
    __shared__ float r1buf[2048];     // R1_j = xT - x_{j+1} (j=255 -> 0)
    __shared__ float WS[8][64];       // per-path-chunk w sums
    __shared__ float PB[2][36 * 128]; // add-reduce buffers (C pairs + S3 pairs)

    const float* prow = path + n * 2048;
    { const int i4 = t * 4; *(float4*)&pbuf[i4] = *(const float4*)&prow[i4]; }
    __syncthreads();
    {
        const int i4 = t * 4;
        if (i4 < NSEG * 8) {
            const float4 xv0 = *(const float4*)&pbuf[i4];
            const float4 xv1 = *(const float4*)&pbuf[i4 + 8];
            *(float4*)&dbuf[i4] = make_float4(xv1.x - xv0.x, xv1.y - xv0.y,
                                              xv1.z - xv0.z, xv1.w - xv0.w);
            const float4 xt = *(const float4*)&pbuf[2040 + (i4 & 4)];
            *(float4*)&r1buf[i4] = make_float4(xt.x - xv1.x, xt.y - xv1.y,
                                               xt.z - xv1.z, xt.w - xv1.w);
        } else {
            *(float4*)&dbuf[i4]  = make_float4(0.f, 0.f, 0.f, 0.f);
            *(float4*)&r1buf[i4] = make_float4(0.f, 0.f, 0.f, 0.f);
        }
    }
    __syncthreads();

    // ---- phase A: wave w computes w-sum of path-chunk w (32 segs) ----
    {
        float xh = pbuf[(w << 8) + a] - pbuf[a];   // x_{32w} - x0
        float wsum = 0.f;
        #pragma unroll 8
        for (int k = (w << 5); k < (w << 5) + 32; ++k) {
            const float da = dbuf[k * 8 + a], db = dbuf[k * 8 + b];
            wsum = fmaf(db, fmaf(0.5f, da, xh), wsum);
            xh += da;
        }
        WS[w][l] = wsum;
    }
    __syncthreads();

    // ---- exclusive S2 prefix for this wave's 8-segment window ----
    float S2w = 0.f;
    for (int m = 0; m < cb; ++m) S2w += WS[m][l];
    const int jstart = (cb << 5) + (pr << 3);
    float S1a = pbuf[(cb << 8) + a] - pbuf[a];     // x_{32cb} - x0
    for (int k = (cb << 5); k < jstart; ++k) {     // <= 24 fine steps
        const float da = dbuf[k * 8 + a], db = dbuf[k * 8 + b];
        S2w = fmaf(db, fmaf(0.5f, da, S1a), S2w);
        S1a += da;
    }
    // S1a = x_{jstart} - x0 ; S2w = S2pre at jstart

    // ---- phase B: 8 segments, half c-range (c in [4h, 4h+4)) ----
    v2f C[16];          // C[ci*4+eh] = S4[l][4h+ci][2eh..2eh+1] partial
    v2f S3C[2];         // S3C[ch]    = S3[l][4h+2ch..+1] partial
    #pragma unroll
    for (int j = 0; j < 16; ++j) C[j] = (v2f)0.f;
    S3C[0] = (v2f)0.f; S3C[1] = (v2f)0.f;

    #pragma unroll
    for (int ss = 0; ss < 8; ++ss) {
        const int j = jstart + ss;
        const v2f dp0 = *(const v2f*)&dbuf[j * 8 + 0];
        const v2f dp1 = *(const v2f*)&dbuf[j * 8 + 2];
        const v2f dp2 = *(const v2f*)&dbuf[j * 8 + 4];
        const v2f dp3 = *(const v2f*)&dbuf[j * 8 + 6];
        const v2f r0 = *(const v2f*)&r1buf[j * 8 + 0];
        const v2f r1 = *(const v2f*)&r1buf[j * 8 + 2];
        const v2f r2 = *(const v2f*)&r1buf[j * 8 + 4];
        const v2f r3 = *(const v2f*)&r1buf[j * 8 + 6];
        const float da = dbuf[j * 8 + a], db = dbuf[j * 8 + b];
        const float dab = da * db;
        const float sdb = S1a * db;
        const float Q = fmaf(dab, INV6,  fmaf(sdb, 0.5f, S2w));
        const float P = fmaf(dab, INV24, fmaf(sdb, INV6, 0.5f * S2w));
        const v2f Qv = Q, Pv = P;
        v2f E[4];
        E[0] = __builtin_elementwise_fma(Qv, r0, Pv * dp0);
        E[1] = __builtin_elementwise_fma(Qv, r1, Pv * dp1);
        E[2] = __builtin_elementwise_fma(Qv, r2, Pv * dp2);
        E[3] = __builtin_elementwise_fma(Qv, r3, Pv * dp3);
        const v2f cpl = h ? dp2 : dp0;   // own c pair (4h, 4h+1)
        const v2f cph = h ? dp3 : dp1;   // own c pair (4h+2, 4h+3)
        const float dcs[4] = {cpl.x, cpl.y, cph.x, cph.y};
        #pragma unroll
        for (int ci = 0; ci < 4; ++ci) {
            const v2f dcv = dcs[ci];
            #pragma unroll
            for (int eh = 0; eh < 4; ++eh)
                C[ci * 4 + eh] = __builtin_elementwise_fma(dcv, E[eh], C[ci * 4 + eh]);
        }
        S3C[0] = __builtin_elementwise_fma(Qv, cpl, S3C[0]);
        S3C[1] = __builtin_elementwise_fma(Qv, cph, S3C[1]);
        S2w = fmaf(db, fmaf(0.5f, da, S1a), S2w);
        S1a += da;
    }

    // ---- intra-block add-reduce over the 4 pairs (pure pk adds) ----
    // slot: C -> (4h+ci)*4+eh in [0,32); S3 -> 32 + 2h + ch
    #pragma unroll
    for (int r = 0; r < 2; ++r) {
        const bool pub = (r == 0) ? (pr & 1) : (pr == 2);
        const bool abs_ = (r == 0) ? !(pr & 1) : (pr == 0);
        const int buf = (r == 0) ? (pr >> 1) : 0;
        if (pub) {
            #pragma unroll
            for (int ci = 0; ci < 4; ++ci)
                #pragma unroll
                for (int eh = 0; eh < 4; ++eh)
                    *(v2f*)&PB[buf][(((4*h + ci)*4 + eh)) * 128 + 2*l] = C[ci*4 + eh];
            *(v2f*)&PB[buf][(32 + 2*h) * 128 + 2*l] = S3C[0];
            *(v2f*)&PB[buf][(33 + 2*h) * 128 + 2*l] = S3C[1];
        }
        __syncthreads();
        if (abs_) {
            #pragma unroll
            for (int ci = 0; ci < 4; ++ci)
                #pragma unroll
                for (int eh = 0; eh < 4; ++eh)
                    C[ci*4 + eh] += *(const v2f*)&PB[buf][(((4*h + ci)*4 + eh)) * 128 + 2*l];
            S3C[0] += *(const v2f*)&PB[buf][(32 + 2*h) * 128 + 2*l];
            S3C[1] += *(const v2f*)&PB[buf][(33 + 2*h) * 128 + 2*l];
        }
        __syncthreads();
    }

    // ---- pair 0 adds the block's contribution to global (HW f32 atomics) ----
    if (pr == 0) {
        float* o = out + n * SIGLEN;
        #pragma unroll
        for (int ci = 0; ci < 4; ++ci)
            #pragma unroll
            for (int eh = 0; eh < 4; ++eh) {
                unsafeAtomicAdd(&o[584 + l*64 + (4*h + ci)*8 + 2*eh],     C[ci*4 + eh].x);
                unsafeAtomicAdd(&o[584 + l*64 + (4*h + ci)*8 + 2*eh + 1], C[ci*4 + eh].y);
            }
        unsafeAtomicAdd(&o[72 + l*8 + 4*h + 0], S3C[0].x);
        unsafeAtomicAdd(&o[72 + l*8 + 4*h + 1], S3C[0].y);
        unsafeAtomicAdd(&o[72 + l*8 + 4*h + 2], S3C[1].x);
        unsafeAtomicAdd(&o[72 + l*8 + 4*h + 3], S3C[1].y);
        if (h == 0) {
            unsafeAtomicAdd(&o[8 + l], WS[cb][l]);         // S2 chunk sum
            if (cb == 0 && b == 0)
                o[a] = pbuf[2040 + a] - pbuf[a];           // S1 (single writer)
        }
    }
}

extern "C" void kernel_launch(void* const* d_in, const int* in_sizes, int n_in,
                              void* d_out, int out_size, void* d_ws, size_t ws_size,
                              hipStream_t stream) {
    const float* path = (const float*)d_in[0];
    float* out = (float*)d_out;
    hipMemsetAsync(d_out, 0, (size_t)out_size * sizeof(float), stream);
    sig_kernel<<<NBATCH * 8, 512, 0, stream>>>(path, out);
}

// Round 16
// 18.566 us; speedup vs baseline: 3.9762x; 3.9762x over previous
//
#include <hip/hip_runtime.h>

#define NBATCH 32
#define NSEG 255
#define SIGLEN 4680       // 8 + 64 + 512 + 4096
#define INV6 (1.0f/6.0f)
#define INV24 (1.0f/24.0f)

typedef float v2f __attribute__((ext_vector_type(2)));

// Commutative ("moment") form of the depth-4 signature (verified R15):
//   S1[e]    = (xT - x0)[e]
//   S2[ab]   = sum_k w_k,  w_k = d_k[b]*(x_k-x0)[a] + 0.5*d_k[a]*d_k[b]
//   Q_j[ab]  = d_a d_b/6  + (x_j-x0)[a] d_b/2 + S2pre_j[ab]
//   P_j[ab]  = d_a d_b/24 + (x_j-x0)[a] d_b/6 + S2pre_j[ab]/2
//   S3[abc]  = sum_j Q_j[ab] d_j[c]
//   S4[abce] = sum_j d_j[c] * ( Q_j[ab]*(xT-x_{j+1})[e] + P_j[ab]*d_j[e] )
// All S3/S4 summands are independent given the scalar prefix S2pre ->
// wave chunks combine by pure ADDITION (no Chen product anywhere).
//
// One block per batch; 512 threads = 8 waves. Wave w owns segments
// [32w, 32w+32) with FULL c-range per lane (l=(a<<3)|b owns S4[a][b][*][*]).
// Phase A: per-chunk w-sums -> WS. Prefix for wave w = sum WS[m<w] (aligned).
// Phase B: 32 segs of C/S3 accumulation. Then 3-round pure-add tree; wave 0
// writes the signature directly. No atomics, no workspace, no memset.
__global__ __launch_bounds__(512)
__attribute__((amdgpu_waves_per_eu(2, 2)))
void sig_kernel(const float* __restrict__ path, float* __restrict__ out) {
    const int n = blockIdx.x;
    const int t = threadIdx.x;
    const int w = t >> 6, l = t & 63, a = l >> 3, b = l & 7;

    __shared__ float pbuf[2048];      // path row
    __shared__ float dbuf[2048];      // d_j (j=255 -> 0 pad)
    __shared__ float r1buf[2048];     // xT - x_{j+1} (j=255 -> 0)
    __shared__ float WS[8][64];       // per-chunk w sums
    __shared__ float PB[4][36 * 128]; // add-reduce buffers (73728 B)

    const float* prow = path + n * 2048;
    { const int i4 = t * 4; *(float4*)&pbuf[i4] = *(const float4*)&prow[i4]; }
    __syncthreads();
    {
        const int i4 = t * 4;
        if (i4 < NSEG * 8) {
            const float4 xv0 = *(const float4*)&pbuf[i4];
            const float4 xv1 = *(const float4*)&pbuf[i4 + 8];
            *(float4*)&dbuf[i4] = make_float4(xv1.x - xv0.x, xv1.y - xv0.y,
                                              xv1.z - xv0.z, xv1.w - xv0.w);
            const float4 xt = *(const float4*)&pbuf[2040 + (i4 & 4)];
            *(float4*)&r1buf[i4] = make_float4(xt.x - xv1.x, xt.y - xv1.y,
                                               xt.z - xv1.z, xt.w - xv1.w);
        } else {
            *(float4*)&dbuf[i4]  = make_float4(0.f, 0.f, 0.f, 0.f);
            *(float4*)&r1buf[i4] = make_float4(0.f, 0.f, 0.f, 0.f);
        }
    }
    __syncthreads();

    // ---- phase A: wave w computes the w-sum of chunk w (32 segs) ----
    {
        float xh = pbuf[(w << 8) + a] - pbuf[a];   // x_{32w}[a] - x0[a]
        float wsum = 0.f;
        #pragma unroll 8
        for (int k = (w << 5); k < (w << 5) + 32; ++k) {
            const float da = dbuf[k * 8 + a], db = dbuf[k * 8 + b];
            wsum = fmaf(db, fmaf(0.5f, da, xh), wsum);
            xh += da;
        }
        WS[w][l] = wsum;
    }
    __syncthreads();

    // ---- exclusive prefix at this wave's window start (aligned: no fine steps) ----
    float S2w = 0.f;
    for (int m = 0; m < w; ++m) S2w += WS[m][l];
    float S1a = pbuf[(w << 8) + a] - pbuf[a];

    // ---- phase B: 32 segments, full c-range ----
    v2f C[32];           // C[c*4+eh] = S4[l][c][2eh..2eh+1] partial
    v2f S3C[4];          // S3C[ch]   = S3[l][2ch..2ch+1] partial
    #pragma unroll
    for (int j = 0; j < 32; ++j) C[j] = (v2f)0.f;
    #pragma unroll
    for (int j = 0; j < 4; ++j) S3C[j] = (v2f)0.f;

    const int jstart = w << 5;
    #pragma unroll 4
    for (int ss = 0; ss < 32; ++ss) {
        const int j = jstart + ss;
        const v2f dp[4] = {*(const v2f*)&dbuf[j * 8 + 0],
                           *(const v2f*)&dbuf[j * 8 + 2],
                           *(const v2f*)&dbuf[j * 8 + 4],
                           *(const v2f*)&dbuf[j * 8 + 6]};
        const v2f rp[4] = {*(const v2f*)&r1buf[j * 8 + 0],
                           *(const v2f*)&r1buf[j * 8 + 2],
                           *(const v2f*)&r1buf[j * 8 + 4],
                           *(const v2f*)&r1buf[j * 8 + 6]};
        const float da = dbuf[j * 8 + a], db = dbuf[j * 8 + b];
        const float dab = da * db;
        const float sdb = S1a * db;
        const float Q = fmaf(dab, INV6,  fmaf(sdb, 0.5f, S2w));
        const float P = fmaf(dab, INV24, fmaf(sdb, INV6, 0.5f * S2w));
        const v2f Qv = Q, Pv = P;
        v2f E[4];
        #pragma unroll
        for (int eh = 0; eh < 4; ++eh)
            E[eh] = __builtin_elementwise_fma(Qv, rp[eh], Pv * dp[eh]);
        const float dcs[8] = {dp[0].x, dp[0].y, dp[1].x, dp[1].y,
                              dp[2].x, dp[2].y, dp[3].x, dp[3].y};
        #pragma unroll
        for (int c = 0; c < 8; ++c) {
            const v2f dcv = dcs[c];
            #pragma unroll
            for (int eh = 0; eh < 4; ++eh)
                C[c * 4 + eh] = __builtin_elementwise_fma(dcv, E[eh], C[c * 4 + eh]);
        }
        #pragma unroll
        for (int ch = 0; ch < 4; ++ch)
            S3C[ch] = __builtin_elementwise_fma(Qv, dp[ch], S3C[ch]);
        S2w = fmaf(db, fmaf(0.5f, da, S1a), S2w);
        S1a += da;
    }

    // ---- 3-round pure-add tree over waves; wave 0 ends with full sums ----
    #pragma unroll
    for (int r = 0; r < 3; ++r) {
        const int stride = 1 << r;
        const int m = (stride << 1) - 1;
        const int buf = w >> (r + 1);
        if ((w & m) == stride) {
            #pragma unroll
            for (int s = 0; s < 32; ++s)
                *(v2f*)&PB[buf][s * 128 + 2 * l] = C[s];
            #pragma unroll
            for (int ch = 0; ch < 4; ++ch)
                *(v2f*)&PB[buf][(32 + ch) * 128 + 2 * l] = S3C[ch];
        }
        __syncthreads();
        if ((w & m) == 0) {
            #pragma unroll
            for (int s = 0; s < 32; ++s)
                C[s] += *(const v2f*)&PB[buf][s * 128 + 2 * l];
            #pragma unroll
            for (int ch = 0; ch < 4; ++ch)
                S3C[ch] += *(const v2f*)&PB[buf][(32 + ch) * 128 + 2 * l];
        }
        __syncthreads();
    }

    // ---- wave 0 writes [S1|S2|S3|S4] ----
    if (w == 0) {
        float* o = out + n * SIGLEN;
        if (b == 0) o[a] = pbuf[2040 + a] - pbuf[a];
        {
            float s2 = WS[0][l];
            #pragma unroll
            for (int m2 = 1; m2 < 8; ++m2) s2 += WS[m2][l];
            o[8 + l] = s2;
        }
        *(float4*)&o[72 + l * 8]     = make_float4(S3C[0].x, S3C[0].y, S3C[1].x, S3C[1].y);
        *(float4*)&o[72 + l * 8 + 4] = make_float4(S3C[2].x, S3C[2].y, S3C[3].x, S3C[3].y);
        #pragma unroll
        for (int c = 0; c < 8; ++c) {
            *(float4*)&o[584 + l * 64 + c * 8] =
                make_float4(C[c*4+0].x, C[c*4+0].y, C[c*4+1].x, C[c*4+1].y);
            *(float4*)&o[584 + l * 64 + c * 8 + 4] =
                make_float4(C[c*4+2].x, C[c*4+2].y, C[c*4+3].x, C[c*4+3].y);
        }
    }
}

extern "C" void kernel_launch(void* const* d_in, const int* in_sizes, int n_in,
                              void* d_out, int out_size, void* d_ws, size_t ws_size,
                              hipStream_t stream) {
    const float* path = (const float*)d_in[0];
    float* out = (float*)d_out;
    sig_kernel<<<NBATCH, 512, 0, stream>>>(path, out);
}